// Round 6
// baseline (174.835 us; speedup 1.0000x reference)
//
#include <hip/hip_runtime.h>
#include <hip/hip_bf16.h>

typedef unsigned short u16;
typedef __attribute__((ext_vector_type(8))) short bf16x8;
typedef __attribute__((ext_vector_type(4))) float f32x4;

typedef const __attribute__((address_space(1))) void gvoid_t;
typedef __attribute__((address_space(3))) void lvoid_t;

__device__ __forceinline__ void gload_lds16(const void* g, void* l) {
  __builtin_amdgcn_global_load_lds((gvoid_t*)g, (lvoid_t*)l, 16, 0, 0);
}

__device__ __forceinline__ u16 f2bf(float f) {
  union { float f; unsigned u; } a;
  a.f = f;
  unsigned r = (a.u + 0x7FFFu + ((a.u >> 16) & 1u)) >> 16;  // RN-even
  return (u16)r;
}

// ---------------------------------------------------------------------------
// Prep: fp32 -> bf16 copies of x and y, plus per-row sum of squares.
// ---------------------------------------------------------------------------
__global__ __launch_bounds__(128) void rbf_prep(
    const float* __restrict__ x, const float* __restrict__ y,
    u16* __restrict__ xb, u16* __restrict__ yb,
    float* __restrict__ xsq, float* __restrict__ ysq,
    int N, int M, int D) {
  int row = blockIdx.x;
  const float* src;
  u16* dst;
  float* sq;
  if (row < N) {
    src = x + (size_t)row * D;
    dst = xb + (size_t)row * D;
    sq = xsq + row;
  } else {
    int r = row - N;
    src = y + (size_t)r * D;
    dst = yb + (size_t)r * D;
    sq = ysq + r;
  }
  int t = threadIdx.x;
  float4 v = reinterpret_cast<const float4*>(src)[t];
  float s = v.x * v.x + v.y * v.y + v.z * v.z + v.w * v.w;
  ushort4 o;
  o.x = f2bf(v.x);
  o.y = f2bf(v.y);
  o.z = f2bf(v.z);
  o.w = f2bf(v.w);
  reinterpret_cast<ushort4*>(dst)[t] = o;
  #pragma unroll
  for (int off = 32; off > 0; off >>= 1) s += __shfl_down(s, off, 64);
  __shared__ float red[2];
  if ((t & 63) == 0) red[t >> 6] = s;
  __syncthreads();
  if (t == 0) sq[0] = red[0] + red[1];
}

// ---------------------------------------------------------------------------
// 128x128 tile, BK=64, 4 waves (2Mx2N, 64x64 each).
// STRUCTURAL CHANGE (R6): only x staged in LDS (32 KiB dbuf); y-fragments
// load DIRECT from global (L2-resident panels; each wave-load = 16 rows x
// 64 B = dense lines). LDS-port time ~halves (55 -> ~27 us/CU) and
// __launch_bounds__(256,3) -> 3 blocks/CU (VGPR <= 170) for overlap of the
// ~40 us store stream with other blocks' K-loops.
// x swizzle: chunk ^= row&7 both sides (involution). Swapped MFMA operands:
// D[j][i] -> per-thread regs = 4 consecutive output columns -> float4 stores.
// Supertile: XCD owns 8 tile-cols, walks 8x8 regions (L2-resident panels).
// ---------------------------------------------------------------------------
#define BM 128
#define BN 128
#define BK 64

__global__ __launch_bounds__(256, 3) void rbf_gemm(
    const u16* __restrict__ xb, const u16* __restrict__ yb,
    const float* __restrict__ xsq, const float* __restrict__ ysq,
    const float* __restrict__ gptr, float* __restrict__ out,
    int N, int M, int D) {
  __shared__ u16 xlds[2][BM * BK];  // 32 KiB

  int bid = blockIdx.x;
  int nbr = N / BM, nbc = M / BN;
  int trow, tcol;
  if (nbr == 64 && nbc == 64) {
    // XCD x owns tile-columns x*8..x*8+7, walked in 8x8-tile regions
    // (column-major inside a region): resident panels stay in that XCD's L2.
    int xcd = bid & 7;
    int s = bid >> 3;        // 0..511
    int gr = s >> 6;         // region row 0..7
    int q = s & 63;          // within-region, column-major
    trow = gr * 8 + (q & 7);
    tcol = xcd * 8 + (q >> 3);
  } else {
    int cpx = gridDim.x >> 3;
    int swz = (bid & 7) * cpx + (bid >> 3);
    trow = swz / nbc;
    tcol = swz % nbc;
  }
  int brow = trow * BM;
  int bcol = tcol * BN;

  int tid = threadIdx.x;
  int w = tid >> 6;       // wave 0..3
  int lane = tid & 63;
  int wm = w >> 1;        // 0..1 row half of x-tile (64 rows)
  int wn = w & 1;         // 0..1 col half (y rows)
  int fr = lane & 15;
  int fq = lane >> 4;

  // --- x staging: wave w stages rows w*32..w*32+31; 4 gloads (8 rows each).
  int srow = lane >> 3;                        // 0..7
  int scol = ((lane & 7) ^ srow) * 8;          // inverse-swizzled source col
  const u16* xsrc = xb + (size_t)(brow + w * 32 + srow) * D + scol;
  int sdst = w * 2048;  // 32 rows * 64 elems

  // --- x fragment read offsets: chunk ^= (row&7) ---
  int cxor = (fr & 7) * 8;
  int colx0 = (fq * 8) ^ cxor;        // kk=0
  int colx1 = (32 + fq * 8) ^ cxor;   // kk=1
  int arow0 = (wm * 64 + fr) * 64;

  // --- y fragment base (direct global; rows = output cols j) ---
  const u16* yrow = yb + (size_t)(bcol + wn * 64 + fr) * D;

  f32x4 acc[4][4];
  #pragma unroll
  for (int m = 0; m < 4; ++m)
    #pragma unroll
    for (int n = 0; n < 4; ++n)
      acc[m][n] = (f32x4){0.f, 0.f, 0.f, 0.f};

  auto stage = [&](int kt, int b) {
    const u16* xs = xsrc + kt * 64;
    u16* la = &xlds[b][sdst];
    #pragma unroll
    for (int i = 0; i < 4; ++i)
      gload_lds16(xs + (size_t)i * 8 * D, la + i * 512);
  };

  int nkt = D >> 6;  // 8
  stage(0, 0);
  stage(1, 1);
  for (int t = 0; t < nkt; ++t) {
    int b = t & 1;
    // stage(t)'s 4 loads landed; stage(t+1)'s 4 stay in flight
    if (t + 1 < nkt)
      asm volatile("s_waitcnt vmcnt(4)" ::: "memory");
    else
      asm volatile("s_waitcnt vmcnt(0)" ::: "memory");
    __builtin_amdgcn_sched_barrier(0);
    __builtin_amdgcn_s_barrier();  // all waves' x-tile-t data visible
    __builtin_amdgcn_sched_barrier(0);

    // y-fragments for tile t: direct global loads (issue first, ~L2 latency
    // hidden by x ds_reads + cross-block TLP at 3 blocks/CU)
    bf16x8 bf[4][2];
    #pragma unroll
    for (int n = 0; n < 4; ++n) {
      bf[n][0] = *(const bf16x8*)&yrow[(size_t)n * 16 * D + t * 64 + fq * 8];
      bf[n][1] = *(const bf16x8*)&yrow[(size_t)n * 16 * D + t * 64 + 32 + fq * 8];
    }

    const u16* A = &xlds[b][0];
    bf16x8 af[4][2];
    #pragma unroll
    for (int m = 0; m < 4; ++m) {
      af[m][0] = *(const bf16x8*)&A[arow0 + m * 1024 + colx0];
      af[m][1] = *(const bf16x8*)&A[arow0 + m * 1024 + colx1];
    }

    // Swapped operands: D[j][i], j = fq*4 + r, i = fr.
    __builtin_amdgcn_s_setprio(1);
    #pragma unroll
    for (int m = 0; m < 4; ++m)
      #pragma unroll
      for (int n = 0; n < 4; ++n) {
        acc[m][n] = __builtin_amdgcn_mfma_f32_16x16x32_bf16(
            bf[n][0], af[m][0], acc[m][n], 0, 0, 0);
        acc[m][n] = __builtin_amdgcn_mfma_f32_16x16x32_bf16(
            bf[n][1], af[m][1], acc[m][n], 0, 0, 0);
      }
    __builtin_amdgcn_s_setprio(0);

    // my x ds_reads of buf b done before anyone re-stages into it
    asm volatile("s_waitcnt lgkmcnt(0)" ::: "memory");
    __builtin_amdgcn_sched_barrier(0);
    __builtin_amdgcn_s_barrier();
    __builtin_amdgcn_sched_barrier(0);
    if (t + 2 < nkt) stage(t + 2, b);
  }

  // Epilogue: out = exp2(2*gl2*acc - gl2*|x|^2 - gl2*|y|^2), clamped <= 2^0.
  float gl2 = gptr[0] * 1.44269504088896f;  // gamma * log2(e)
  float m2gl2 = 2.0f * gl2;
  float4 gys[4];
  #pragma unroll
  for (int n = 0; n < 4; ++n) {
    float4 t4 = *reinterpret_cast<const float4*>(
        &ysq[bcol + wn * 64 + n * 16 + fq * 4]);
    gys[n].x = gl2 * t4.x;
    gys[n].y = gl2 * t4.y;
    gys[n].z = gl2 * t4.z;
    gys[n].w = gl2 * t4.w;
  }
  #pragma unroll
  for (int m = 0; m < 4; ++m) {
    int i = brow + wm * 64 + m * 16 + fr;
    float gxs = gl2 * xsq[i];
    size_t ro = (size_t)i * M;
    #pragma unroll
    for (int n = 0; n < 4; ++n) {
      int jb = bcol + wn * 64 + n * 16 + fq * 4;
      float4 e;
      e.x = exp2f(fminf(fmaf(m2gl2, acc[m][n][0], -(gxs + gys[n].x)), 0.f));
      e.y = exp2f(fminf(fmaf(m2gl2, acc[m][n][1], -(gxs + gys[n].y)), 0.f));
      e.z = exp2f(fminf(fmaf(m2gl2, acc[m][n][2], -(gxs + gys[n].z)), 0.f));
      e.w = exp2f(fminf(fmaf(m2gl2, acc[m][n][3], -(gxs + gys[n].w)), 0.f));
      *reinterpret_cast<float4*>(&out[ro + jb]) = e;
    }
  }
}

// ---------------------------------------------------------------------------
// Fallback: fp32 LDS-tiled, slow but correct for odd shapes.
// ---------------------------------------------------------------------------
__global__ __launch_bounds__(256) void rbf_naive(
    const float* __restrict__ x, const float* __restrict__ y,
    const float* __restrict__ gptr, float* __restrict__ out,
    int N, int M, int D) {
  __shared__ float xs[16][17];
  __shared__ float ys[16][17];
  int nbn = M / 16;
  int brow = (blockIdx.x / nbn) * 16;
  int bcol = (blockIdx.x % nbn) * 16;
  int ti = threadIdx.x >> 4, tj = threadIdx.x & 15;
  float dacc = 0.f, xacc = 0.f, yacc = 0.f;
  for (int k0 = 0; k0 < D; k0 += 16) {
    xs[ti][tj] = x[(size_t)(brow + ti) * D + k0 + tj];
    ys[ti][tj] = y[(size_t)(bcol + ti) * D + k0 + tj];
    __syncthreads();
    #pragma unroll
    for (int kk = 0; kk < 16; ++kk) {
      float xv = xs[ti][kk], yv = ys[tj][kk];
      dacc += xv * yv;
      xacc += xv * xv;
      yacc += yv * yv;
    }
    __syncthreads();
  }
  float gamma = gptr[0];
  float d2 = fmaxf(xacc + yacc - 2.f * dacc, 0.f);
  out[(size_t)(brow + ti) * M + (bcol + tj)] = __expf(-gamma * d2);
}

// ---------------------------------------------------------------------------
extern "C" void kernel_launch(void* const* d_in, const int* in_sizes, int n_in,
                              void* d_out, int out_size, void* d_ws,
                              size_t ws_size, hipStream_t stream) {
  const float* x = (const float*)d_in[0];
  const float* y = (const float*)d_in[1];
  const float* g = (const float*)d_in[2];
  float* out = (float*)d_out;

  const int D = 512;
  const int N = in_sizes[0] / D;
  const int M = in_sizes[1] / D;

  size_t need = (size_t)(N + M) * D * sizeof(u16) + (size_t)(N + M) * sizeof(float);
  bool shapes_ok = (N % BM == 0) && (M % BN == 0) && (D % BK == 0) && (D / BK >= 2);

  if (ws_size >= need && shapes_ok) {
    u16* xb = (u16*)d_ws;
    u16* yb = xb + (size_t)N * D;
    float* xsq = (float*)(yb + (size_t)M * D);
    float* ysq = xsq + N;

    rbf_prep<<<N + M, 128, 0, stream>>>(x, y, xb, yb, xsq, ysq, N, M, D);
    int nwg = (N / BM) * (M / BN);
    rbf_gemm<<<nwg, 256, 0, stream>>>(xb, yb, xsq, ysq, g, out, N, M, D);
  } else {
    rbf_naive<<<(N / 16) * (M / 16), 256, 0, stream>>>(x, y, g, out, N, M, D);
  }
}

// Round 7
// 118.436 us; speedup vs baseline: 1.4762x; 1.4762x over previous
//
#include <hip/hip_runtime.h>
#include <hip/hip_bf16.h>

typedef unsigned short u16;
typedef __attribute__((ext_vector_type(8))) short bf16x8;
typedef __attribute__((ext_vector_type(4))) float f32x4;

typedef const __attribute__((address_space(1))) void gvoid_t;
typedef __attribute__((address_space(3))) void lvoid_t;

__device__ __forceinline__ void gload_lds16(const void* g, void* l) {
  __builtin_amdgcn_global_load_lds((gvoid_t*)g, (lvoid_t*)l, 16, 0, 0);
}

__device__ __forceinline__ u16 f2bf(float f) {
  union { float f; unsigned u; } a;
  a.f = f;
  unsigned r = (a.u + 0x7FFFu + ((a.u >> 16) & 1u)) >> 16;  // RN-even
  return (u16)r;
}

// ---------------------------------------------------------------------------
// Prep: fp32 -> bf16 copies of x and y, plus per-row sum of squares.
// ---------------------------------------------------------------------------
__global__ __launch_bounds__(128) void rbf_prep(
    const float* __restrict__ x, const float* __restrict__ y,
    u16* __restrict__ xb, u16* __restrict__ yb,
    float* __restrict__ xsq, float* __restrict__ ysq,
    int N, int M, int D) {
  int row = blockIdx.x;
  const float* src;
  u16* dst;
  float* sq;
  if (row < N) {
    src = x + (size_t)row * D;
    dst = xb + (size_t)row * D;
    sq = xsq + row;
  } else {
    int r = row - N;
    src = y + (size_t)r * D;
    dst = yb + (size_t)r * D;
    sq = ysq + r;
  }
  int t = threadIdx.x;
  float4 v = reinterpret_cast<const float4*>(src)[t];
  float s = v.x * v.x + v.y * v.y + v.z * v.z + v.w * v.w;
  ushort4 o;
  o.x = f2bf(v.x);
  o.y = f2bf(v.y);
  o.z = f2bf(v.z);
  o.w = f2bf(v.w);
  reinterpret_cast<ushort4*>(dst)[t] = o;
  #pragma unroll
  for (int off = 32; off > 0; off >>= 1) s += __shfl_down(s, off, 64);
  __shared__ float red[2];
  if ((t & 63) == 0) red[t >> 6] = s;
  __syncthreads();
  if (t == 0) sq[0] = red[0] + red[1];
}

// ---------------------------------------------------------------------------
// 128x128 tile, BK=32, 4 waves (2Mx2N, 64x64 each), LDS 32 KiB dbuf ->
// 4 blocks/CU (16 waves/CU) -- the latency-hiding fix for R6's measured
// latency-bound profile (MfmaUtil 16%, VALUBusy 20%, Occ 32%).
// Both operands staged via global_load_lds. NO swizzle needed at BK=32:
// row stride 64 B => fragment ds_read_b128 is naturally bank-balanced
// (8 accesses/bank = 1KB/instr minimum).
// Counted vmcnt(4): stage(t+1)'s 4 loads stay in flight across tile t.
// Swapped MFMA operands: D[j][i] -> per-thread regs = 4 consecutive output
// columns -> float4 stores. Supertile: XCD owns 8 tile-cols, 8x8 regions.
// exp2-fused epilogue: gamma*log2e folded into norms.
// ---------------------------------------------------------------------------
#define BM 128
#define BN 128
#define BK 32

__global__ __launch_bounds__(256, 4) void rbf_gemm(
    const u16* __restrict__ xb, const u16* __restrict__ yb,
    const float* __restrict__ xsq, const float* __restrict__ ysq,
    const float* __restrict__ gptr, float* __restrict__ out,
    int N, int M, int D) {
  __shared__ u16 lds[2][2][BM * BK];  // 32 KiB

  int bid = blockIdx.x;
  int nbr = N / BM, nbc = M / BN;
  int trow, tcol;
  if (nbr == 64 && nbc == 64) {
    // XCD x owns tile-columns x*8..x*8+7, walked in 8x8-tile regions
    // (column-major inside a region): panels stay L2-resident per XCD.
    int xcd = bid & 7;
    int s = bid >> 3;        // 0..511
    int gr = s >> 6;         // region row 0..7
    int q = s & 63;          // within-region, column-major
    trow = gr * 8 + (q & 7);
    tcol = xcd * 8 + (q >> 3);
  } else {
    int cpx = gridDim.x >> 3;
    int swz = (bid & 7) * cpx + (bid >> 3);
    trow = swz / nbc;
    tcol = swz % nbc;
  }
  int brow = trow * BM;
  int bcol = tcol * BN;

  int tid = threadIdx.x;
  int w = tid >> 6;       // wave 0..3
  int lane = tid & 63;
  int wm = w >> 1;        // 0..1 row half (64 rows)
  int wn = w & 1;         // 0..1 col half (64 cols)
  int fr = lane & 15;
  int fq = lane >> 4;

  // --- staging: wave w stages rows w*32..w*32+31 of A and B.
  // One gload instr = 64 lanes x 16B = 16 rows (row = 64 B at BK=32).
  int srow = lane >> 2;                 // 0..15
  int schunk = (lane & 3) * 8;          // elems (16B chunks)
  const u16* xsrc = xb + (size_t)(brow + w * 32 + srow) * D + schunk;
  const u16* ysrc = yb + (size_t)(bcol + w * 32 + srow) * D + schunk;
  int sdst = w * 1024;  // 32 rows * 32 elems

  // --- fragment read offsets (linear, bank-balanced) ---
  int colf = fq * 8;
  int arow0 = (wm * 64 + fr) * 32 + colf;
  int brow0 = (wn * 64 + fr) * 32 + colf;

  f32x4 acc[4][4];
  #pragma unroll
  for (int m = 0; m < 4; ++m)
    #pragma unroll
    for (int n = 0; n < 4; ++n)
      acc[m][n] = (f32x4){0.f, 0.f, 0.f, 0.f};

  auto stage = [&](int kt, int b) {
    const u16* xs = xsrc + kt * 32;
    const u16* ys = ysrc + kt * 32;
    u16* la = &lds[b][0][sdst];
    u16* lb = &lds[b][1][sdst];
    gload_lds16(xs, la);
    gload_lds16(xs + (size_t)16 * D, la + 512);
    gload_lds16(ys, lb);
    gload_lds16(ys + (size_t)16 * D, lb + 512);
  };

  int nkt = D >> 5;  // 16
  stage(0, 0);
  stage(1, 1);
  for (int t = 0; t < nkt; ++t) {
    int b = t & 1;
    // stage(t)'s 4 loads landed; stage(t+1)'s 4 stay in flight
    if (t + 1 < nkt)
      asm volatile("s_waitcnt vmcnt(4)" ::: "memory");
    else
      asm volatile("s_waitcnt vmcnt(0)" ::: "memory");
    __builtin_amdgcn_sched_barrier(0);
    __builtin_amdgcn_s_barrier();  // all waves' tile-t data visible
    __builtin_amdgcn_sched_barrier(0);

    const u16* A = &lds[b][0][0];
    const u16* B = &lds[b][1][0];
    bf16x8 af[4], bf[4];
    #pragma unroll
    for (int m = 0; m < 4; ++m)
      af[m] = *(const bf16x8*)&A[arow0 + m * 512];
    #pragma unroll
    for (int n = 0; n < 4; ++n)
      bf[n] = *(const bf16x8*)&B[brow0 + n * 512];

    // Swapped operands: D[j][i], j = fq*4 + r, i = fr.
    __builtin_amdgcn_s_setprio(1);
    #pragma unroll
    for (int m = 0; m < 4; ++m)
      #pragma unroll
      for (int n = 0; n < 4; ++n)
        acc[m][n] = __builtin_amdgcn_mfma_f32_16x16x32_bf16(
            bf[n], af[m], acc[m][n], 0, 0, 0);
    __builtin_amdgcn_s_setprio(0);

    // my ds_reads of buf b done before anyone re-stages into it
    asm volatile("s_waitcnt lgkmcnt(0)" ::: "memory");
    __builtin_amdgcn_sched_barrier(0);
    __builtin_amdgcn_s_barrier();
    __builtin_amdgcn_sched_barrier(0);
    if (t + 2 < nkt) stage(t + 2, b);
  }

  // Epilogue: out = exp2(2*gl2*acc - gl2*|x|^2 - gl2*|y|^2), clamped <= 2^0.
  float gl2 = gptr[0] * 1.44269504088896f;  // gamma * log2(e)
  float m2gl2 = 2.0f * gl2;
  float4 gys[4];
  #pragma unroll
  for (int n = 0; n < 4; ++n) {
    float4 t4 = *reinterpret_cast<const float4*>(
        &ysq[bcol + wn * 64 + n * 16 + fq * 4]);
    gys[n].x = gl2 * t4.x;
    gys[n].y = gl2 * t4.y;
    gys[n].z = gl2 * t4.z;
    gys[n].w = gl2 * t4.w;
  }
  #pragma unroll
  for (int m = 0; m < 4; ++m) {
    int i = brow + wm * 64 + m * 16 + fr;
    float gxs = gl2 * xsq[i];
    size_t ro = (size_t)i * M;
    #pragma unroll
    for (int n = 0; n < 4; ++n) {
      int jb = bcol + wn * 64 + n * 16 + fq * 4;
      float4 e;
      e.x = exp2f(fminf(fmaf(m2gl2, acc[m][n][0], -(gxs + gys[n].x)), 0.f));
      e.y = exp2f(fminf(fmaf(m2gl2, acc[m][n][1], -(gxs + gys[n].y)), 0.f));
      e.z = exp2f(fminf(fmaf(m2gl2, acc[m][n][2], -(gxs + gys[n].z)), 0.f));
      e.w = exp2f(fminf(fmaf(m2gl2, acc[m][n][3], -(gxs + gys[n].w)), 0.f));
      *reinterpret_cast<float4*>(&out[ro + jb]) = e;
    }
  }
}

// ---------------------------------------------------------------------------
// Fallback: fp32 LDS-tiled, slow but correct for odd shapes.
// ---------------------------------------------------------------------------
__global__ __launch_bounds__(256) void rbf_naive(
    const float* __restrict__ x, const float* __restrict__ y,
    const float* __restrict__ gptr, float* __restrict__ out,
    int N, int M, int D) {
  __shared__ float xs[16][17];
  __shared__ float ys[16][17];
  int nbn = M / 16;
  int brow = (blockIdx.x / nbn) * 16;
  int bcol = (blockIdx.x % nbn) * 16;
  int ti = threadIdx.x >> 4, tj = threadIdx.x & 15;
  float dacc = 0.f, xacc = 0.f, yacc = 0.f;
  for (int k0 = 0; k0 < D; k0 += 16) {
    xs[ti][tj] = x[(size_t)(brow + ti) * D + k0 + tj];
    ys[ti][tj] = y[(size_t)(bcol + ti) * D + k0 + tj];
    __syncthreads();
    #pragma unroll
    for (int kk = 0; kk < 16; ++kk) {
      float xv = xs[ti][kk], yv = ys[tj][kk];
      dacc += xv * yv;
      xacc += xv * xv;
      yacc += yv * yv;
    }
    __syncthreads();
  }
  float gamma = gptr[0];
  float d2 = fmaxf(xacc + yacc - 2.f * dacc, 0.f);
  out[(size_t)(brow + ti) * M + (bcol + tj)] = __expf(-gamma * d2);
}

// ---------------------------------------------------------------------------
extern "C" void kernel_launch(void* const* d_in, const int* in_sizes, int n_in,
                              void* d_out, int out_size, void* d_ws,
                              size_t ws_size, hipStream_t stream) {
  const float* x = (const float*)d_in[0];
  const float* y = (const float*)d_in[1];
  const float* g = (const float*)d_in[2];
  float* out = (float*)d_out;

  const int D = 512;
  const int N = in_sizes[0] / D;
  const int M = in_sizes[1] / D;

  size_t need = (size_t)(N + M) * D * sizeof(u16) + (size_t)(N + M) * sizeof(float);
  bool shapes_ok = (N % BM == 0) && (M % BN == 0) && (D % BK == 0) && (D / BK >= 2);

  if (ws_size >= need && shapes_ok) {
    u16* xb = (u16*)d_ws;
    u16* yb = xb + (size_t)N * D;
    float* xsq = (float*)(yb + (size_t)M * D);
    float* ysq = xsq + N;

    rbf_prep<<<N + M, 128, 0, stream>>>(x, y, xb, yb, xsq, ysq, N, M, D);
    int nwg = (N / BM) * (M / BN);
    rbf_gemm<<<nwg, 256, 0, stream>>>(xb, yb, xsq, ysq, g, out, N, M, D);
  } else {
    rbf_naive<<<(N / 16) * (M / 16), 256, 0, stream>>>(x, y, g, out, N, M, D);
  }
}